// Round 10
// baseline (948.821 us; speedup 1.0000x reference)
//
#include <hip/hip_runtime.h>
#include <hip/hip_cooperative_groups.h>
#include <hip/hip_bf16.h>

namespace cg = cooperative_groups;

#define N_NODESC 50000
#define N_EDGESC 1600000
#define SDIM 64
#define VDIM 32
#define HID 96
#define IN_DIMC 163

#define GRID_E 6250
#define TPB_E 4            // tiles per block (25000 tiles / 6250 blocks)
#define NXCD 8
#define XQ (GRID_E / NXCD) // 781
#define XR (GRID_E % NXCD) // 2
#define NPRE 782           // precompute chunks (50000/64 rounded up)
#define SCB 196            // scan blocks (50000 / 256 rounded up)

typedef float f32x4 __attribute__((ext_vector_type(4)));
typedef short s16x8 __attribute__((ext_vector_type(8)));

__device__ __forceinline__ float bf2f(__hip_bfloat16 x) { return __bfloat162float(x); }
__device__ __forceinline__ __hip_bfloat16 f2bf(float x) { return __float2bfloat16(x); }
__device__ __forceinline__ float bfbits2f(short b) {
    unsigned u = ((unsigned)(unsigned short)b) << 16;
    return __builtin_bit_cast(float, u);
}
__device__ __forceinline__ short f2bfbits(float x) {
    __hip_bfloat16 h = __float2bfloat16(x);
    return *(const short*)&h;
}

// ---------------------------------------------------------------------------
// MFMA node-precompute chunk (64 nodes): [P|Q] = hs_bf16 @ [W1a|W1b];
// P (+b1) -> SrcRec[n][0:96), Q -> Qt. LDS-staged, coalesced stores.
__device__ __forceinline__ void precompute_chunk(
    int ch, int t, const float* __restrict__ hs,
    const __hip_bfloat16* __restrict__ WbT2, const float* __restrict__ b1,
    __hip_bfloat16* __restrict__ SrcRec, __hip_bfloat16* __restrict__ Qt,
    __hip_bfloat16 (*sA)[72], __hip_bfloat16 (*sOut)[200]) {
    const int lane = t & 63;
    const int w = t >> 6;
    const int m16 = lane & 15;
    const int q = lane >> 4;
    const int nb = ch * 64;

    for (int idx = t; idx < 64 * 64; idx += 256) {
        int node = idx >> 6, f = idx & 63;
        int g = nb + node;
        sA[node][f] = f2bf(g < N_NODESC ? hs[g * SDIM + f] : 0.f);
    }
    __syncthreads();

    s16x8 bfr[3][2];
    float b1v[3];
    for (int nt = 0; nt < 3; ++nt) {
        int n_out = w * 48 + nt * 16 + m16;
        for (int kt = 0; kt < 2; ++kt)
            bfr[nt][kt] = *(const s16x8*)&WbT2[n_out * 64 + kt * 32 + q * 8];
        b1v[nt] = (n_out < 96) ? b1[n_out] : 0.f;
    }

    for (int ms = 0; ms < 4; ++ms) {
        s16x8 afr[2];
        for (int kt = 0; kt < 2; ++kt)
            afr[kt] = *(const s16x8*)&sA[ms * 16 + m16][kt * 32 + q * 8];
        f32x4 acc[3];
        for (int nt = 0; nt < 3; ++nt) acc[nt] = (f32x4){0.f, 0.f, 0.f, 0.f};
        for (int nt = 0; nt < 3; ++nt)
            for (int kt = 0; kt < 2; ++kt)
                acc[nt] = __builtin_amdgcn_mfma_f32_16x16x32_bf16(
                    afr[kt], bfr[nt][kt], acc[nt], 0, 0, 0);
        for (int nt = 0; nt < 3; ++nt) {
            int n_out = w * 48 + nt * 16 + m16;
            for (int r = 0; r < 4; ++r)
                sOut[ms * 16 + q * 4 + r][n_out] = f2bf(acc[nt][r] + b1v[nt]);
        }
    }
    __syncthreads();

    for (int idx = t; idx < 64 * 12; idx += 256) {
        int node = idx / 12, c2 = idx - (idx / 12) * 12;
        int g = nb + node;
        if (g < N_NODESC)
            *(s16x8*)&SrcRec[g * 128 + c2 * 8] = *(const s16x8*)&sOut[node][c2 * 8];
    }
    for (int idx = t; idx < 64 * 12; idx += 256) {
        int node = idx / 12, c2 = idx - (idx / 12) * 12;
        int g = nb + node;
        if (g < N_NODESC)
            *(s16x8*)&Qt[g * 96 + c2 * 8] = *(const s16x8*)&sOut[node][96 + c2 * 8];
    }
}

// ---------------------------------------------------------------------------
// Cooperative mega-aux: all pre-edge work in ONE launch.
//  A: init out/SrcRec.hv/weight-packs/counts/flag/ctr      -> grid.sync
//  B: dst histogram (all blocks)                            -> grid.sync
//  C1: blocks<196 scan-partials; ALL blocks then drain
//      precompute chunks via atomic work counter            -> grid.sync
//  C2: block 0 scans block-sums                             -> grid.sync
//  C3: blocks<196 apply offsets                             -> grid.sync
//  D: scatter edges to dst-sorted order
__global__ __launch_bounds__(256, 4) void mega_aux(
    const int* __restrict__ ei, int hostflag,
    const float* __restrict__ hs, const float* __restrict__ hv,
    const float* __restrict__ W1, const float* __restrict__ W2,
    const float* __restrict__ b1,
    float* __restrict__ out,
    int* __restrict__ counts, int* __restrict__ cur, int2* __restrict__ edges,
    __hip_bfloat16* __restrict__ SrcRec, __hip_bfloat16* __restrict__ Qt,
    __hip_bfloat16* __restrict__ WbT2, __hip_bfloat16* __restrict__ W1cgT,
    __hip_bfloat16* __restrict__ W2Tb,
    int* __restrict__ flagp, int* __restrict__ bsum, int* __restrict__ boff,
    int* __restrict__ ctr) {
    __shared__ alignas(16) char smem[34944];
    __hip_bfloat16 (*sA)[72] = (__hip_bfloat16(*)[72])smem;              // 9216 B
    __hip_bfloat16 (*sOut)[200] = (__hip_bfloat16(*)[200])(smem + 9216); // 25600 B
    int* s_scan = (int*)smem;                 // 1 KB, used only in scan phases
    int* s_chunk = (int*)(smem + 34816);      // chunk-id broadcast

    cg::grid_group grid = cg::this_grid();
    const int t = threadIdx.x;
    const int blk = blockIdx.x;
    const int gid = blk * 256 + t;
    const int G = gridDim.x * 256;

    // ---- Phase A: init everything ----
    for (int i = gid; i < N_NODESC * (SDIM + VDIM) / 4; i += G) {
        const int HS4 = N_NODESC * SDIM / 4;
        float4 v = (i < HS4) ? ((const float4*)hs)[i] : ((const float4*)hv)[i - HS4];
        ((float4*)out)[i] = v;
    }
    for (int i = gid; i < N_NODESC * VDIM / 8; i += G) {
        int n = i >> 2, c = i & 3;
        const float4* hv4 = (const float4*)hv;
        float4 a = hv4[n * 8 + c * 2];
        float4 bq = hv4[n * 8 + c * 2 + 1];
        s16x8 o;
        o[0] = f2bfbits(a.x);  o[1] = f2bfbits(a.y);
        o[2] = f2bfbits(a.z);  o[3] = f2bfbits(a.w);
        o[4] = f2bfbits(bq.x); o[5] = f2bfbits(bq.y);
        o[6] = f2bfbits(bq.z); o[7] = f2bfbits(bq.w);
        *(s16x8*)&SrcRec[n * 128 + 96 + c * 8] = o;
    }
    for (int i = gid; i < 192 * 64; i += G) {
        int n = i >> 6, k = i & 63;
        float val = (n < 96) ? W1[k * HID + n] : W1[(64 + k) * HID + (n - 96)];
        WbT2[i] = f2bf(val);
    }
    for (int i = gid; i < 96 * 64; i += G) {
        int n = i >> 6, k = i & 63;
        float val = 0.f;
        if (k < 32) val = W1[(128 + k) * HID + n];
        else if (k < 35) val = W1[(160 + (k - 32)) * HID + n];
        W1cgT[i] = f2bf(val);
    }
    for (int i = gid; i < 96 * 96; i += G) {
        int n = i / 96, k = i - (i / 96) * 96;
        W2Tb[i] = f2bf(W2[k * HID + n]);
    }
    for (int i = gid; i < N_NODESC; i += G) counts[i] = 0;
    if (gid == 0) {
        *ctr = 0;
        if (hostflag >= 0) *flagp = hostflag;
        else {
            int z = 1;
            for (int k = 0; k < 64; ++k) if (ei[2 * k + 1] != 0) { z = 0; break; }
            *flagp = z;
        }
    }
    grid.sync();

    // ---- Phase B: dst histogram ----
    const int fl = *flagp;
    for (int e = gid; e < N_EDGESC; e += G) {
        int dN = fl ? (int)((const long long*)ei)[N_EDGESC + e] : ei[N_EDGESC + e];
        atomicAdd(&counts[dN], 1);
    }
    grid.sync();

    // ---- Phase C1: scan partials (196 blocks) + precompute (all, dynamic) ----
    if (blk < SCB) {
        int i = blk * 256 + t;
        int val = (i < N_NODESC) ? counts[i] : 0;
        s_scan[t] = val;
        __syncthreads();
        for (int d = 1; d < 256; d <<= 1) {
            int v = (t >= d) ? s_scan[t - d] : 0;
            __syncthreads();
            s_scan[t] += v;
            __syncthreads();
        }
        if (i < N_NODESC) cur[i] = s_scan[t] - val;
        if (t == 255) bsum[blk] = s_scan[255];
        __syncthreads();
    }
    for (;;) {
        if (t == 0) *s_chunk = atomicAdd(ctr, 1);
        __syncthreads();
        int ch = *s_chunk;
        if (ch >= NPRE) break;
        precompute_chunk(ch, t, hs, WbT2, b1, SrcRec, Qt, sA, sOut);
        __syncthreads();
    }
    grid.sync();

    // ---- Phase C2: scan of block sums (block 0) ----
    if (blk == 0) {
        int val = (t < SCB) ? bsum[t] : 0;
        s_scan[t] = val;
        __syncthreads();
        for (int d = 1; d < 256; d <<= 1) {
            int v = (t >= d) ? s_scan[t - d] : 0;
            __syncthreads();
            s_scan[t] += v;
            __syncthreads();
        }
        if (t < SCB) boff[t] = s_scan[t] - val;
    }
    grid.sync();

    // ---- Phase C3: apply offsets ----
    if (blk < SCB) {
        int i = blk * 256 + t;
        if (i < N_NODESC) cur[i] += boff[blk];
    }
    grid.sync();

    // ---- Phase D: scatter edges ----
    for (int e = gid; e < N_EDGESC; e += G) {
        int sN, dN;
        if (fl) {
            const long long* e64 = (const long long*)ei;
            sN = (int)e64[e]; dN = (int)e64[N_EDGESC + e];
        } else { sN = ei[e]; dN = ei[N_EDGESC + e]; }
        int p = atomicAdd(&cur[dN], 1);
        edges[p] = make_int2(sN, dN);
    }
}

// ---------------------------------------------------------------------------
// ===== Round-9 fallback aux kernels (used if cooperative launch fails) =====
__global__ void detect_zero(const int* ei, int* flag, int* __restrict__ counts) {
    int i = blockIdx.x * blockDim.x + threadIdx.x;
    if (i < N_NODESC) counts[i] = 0;
    if (i == 0) {
        int z = 1;
        for (int k = 0; k < 64; ++k) {
            if (ei[2 * k + 1] != 0) { z = 0; break; }
        }
        *flag = z;
    }
}

__global__ void fused_init(const float* __restrict__ hs, const float* __restrict__ hv,
                           float* __restrict__ out, int* __restrict__ counts,
                           const float* __restrict__ W1, const float* __restrict__ W2,
                           __hip_bfloat16* __restrict__ SrcRec,
                           __hip_bfloat16* __restrict__ WbT2,
                           __hip_bfloat16* __restrict__ W1cgT,
                           __hip_bfloat16* __restrict__ W2Tb,
                           const int* __restrict__ ei, const int* __restrict__ flag64) {
    int i = blockIdx.x * blockDim.x + threadIdx.x;
    if (i < N_NODESC * (SDIM + VDIM) / 4) {
        const int HS4 = N_NODESC * SDIM / 4;
        float4 v = (i < HS4) ? ((const float4*)hs)[i] : ((const float4*)hv)[i - HS4];
        ((float4*)out)[i] = v;
    }
    if (i < N_NODESC * VDIM / 8) {
        int n = i >> 2, c = i & 3;
        const float4* hv4 = (const float4*)hv;
        float4 a = hv4[n * 8 + c * 2];
        float4 bq = hv4[n * 8 + c * 2 + 1];
        s16x8 o;
        o[0] = f2bfbits(a.x);  o[1] = f2bfbits(a.y);
        o[2] = f2bfbits(a.z);  o[3] = f2bfbits(a.w);
        o[4] = f2bfbits(bq.x); o[5] = f2bfbits(bq.y);
        o[6] = f2bfbits(bq.z); o[7] = f2bfbits(bq.w);
        *(s16x8*)&SrcRec[n * 128 + 96 + c * 8] = o;
    }
    if (i < 192 * 64) {
        int n = i >> 6, k = i & 63;
        float val = (n < 96) ? W1[k * HID + n] : W1[(64 + k) * HID + (n - 96)];
        WbT2[i] = f2bf(val);
    }
    if (i < 96 * 64) {
        int n = i >> 6, k = i & 63;
        float val = 0.f;
        if (k < 32) val = W1[(128 + k) * HID + n];
        else if (k < 35) val = W1[(160 + (k - 32)) * HID + n];
        W1cgT[i] = f2bf(val);
    }
    if (i < 96 * 96) {
        int n = i / 96, k = i - (i / 96) * 96;
        W2Tb[i] = f2bf(W2[k * HID + n]);
    }
    {
        int dN;
        if (*flag64) dN = (int)((const long long*)ei)[N_EDGESC + i];
        else dN = ei[N_EDGESC + i];
        atomicAdd(&counts[dN], 1);
    }
}

__global__ __launch_bounds__(256) void scan_partials(
    const int* __restrict__ counts, int* __restrict__ cur, int* __restrict__ bsum) {
    __shared__ int sc[256];
    const int b = blockIdx.x, t = threadIdx.x;
    const int i = b * 256 + t;
    int val = (i < N_NODESC) ? counts[i] : 0;
    sc[t] = val;
    __syncthreads();
    for (int d = 1; d < 256; d <<= 1) {
        int v = (t >= d) ? sc[t - d] : 0;
        __syncthreads();
        sc[t] += v;
        __syncthreads();
    }
    if (i < N_NODESC) cur[i] = sc[t] - val;
    if (t == 255) bsum[b] = sc[255];
}

__global__ __launch_bounds__(256) void scan_bsums(
    const int* __restrict__ bsum, int* __restrict__ boff) {
    __shared__ int sc[256];
    const int t = threadIdx.x;
    int val = (t < SCB) ? bsum[t] : 0;
    sc[t] = val;
    __syncthreads();
    for (int d = 1; d < 256; d <<= 1) {
        int v = (t >= d) ? sc[t - d] : 0;
        __syncthreads();
        sc[t] += v;
        __syncthreads();
    }
    if (t < SCB) boff[t] = sc[t] - val;
}

__global__ __launch_bounds__(256) void scan_apply(
    int* __restrict__ cur, const int* __restrict__ boff) {
    const int i = blockIdx.x * 256 + threadIdx.x;
    if (i < N_NODESC) cur[i] += boff[blockIdx.x];
}

__global__ __launch_bounds__(256, 2) void scatter_precompute(
    const int* __restrict__ ei, const int* __restrict__ flag64,
    int* __restrict__ cur, int2* __restrict__ edges,
    const float* __restrict__ hs, const __hip_bfloat16* __restrict__ WbT2,
    const float* __restrict__ b1,
    __hip_bfloat16* __restrict__ SrcRec, __hip_bfloat16* __restrict__ Qt) {
    __shared__ __hip_bfloat16 sA[64][72];
    __shared__ __hip_bfloat16 sOut[64][200];
    const int blk = blockIdx.x;
    const int t = threadIdx.x;

    if (blk >= NPRE) {
        int e = (blk - NPRE) * 256 + t;
        int sN, dN;
        if (*flag64) {
            const long long* e64 = (const long long*)ei;
            sN = (int)e64[e]; dN = (int)e64[N_EDGESC + e];
        } else { sN = ei[e]; dN = ei[N_EDGESC + e]; }
        int p = atomicAdd(&cur[dN], 1);
        edges[p] = make_int2(sN, dN);
        return;
    }
    precompute_chunk(blk, t, hs, WbT2, b1, SrcRec, Qt, sA, sOut);
}

// ---------------------------------------------------------------------------
// Main edge kernel (unchanged from round 9; proven 217 µs config).
__global__ __launch_bounds__(256, 3) void edge_kernel_sorted(
    const int2* __restrict__ edges,
    const float* __restrict__ pos, const float* __restrict__ ori,
    const __hip_bfloat16* __restrict__ W2Tb, const float* __restrict__ b2,
    const __hip_bfloat16* __restrict__ SrcRec, const __hip_bfloat16* __restrict__ Qt,
    const __hip_bfloat16* __restrict__ W1cgT,
    float* __restrict__ out) {
    __shared__ int s_srcM[2][64], s_dstM[2][64];
    __shared__ alignas(16) __hip_bfloat16 hVG[64][72];    // [0:32) rot-hv, [32:64) geo
    __shared__ alignas(16) __hip_bfloat16 s_vf[64][104];  // vec+geo contrib / msg
    __shared__ alignas(16) short sW2f[18 * 64 * 8];       // W2 frags, lane-packed
    __shared__ int s_segstart[66];

    const int t = threadIdx.x;
    const int lane = t & 63;
    const int w = t >> 6;
    const int m16 = lane & 15;
    const int q = lane >> 4;
    const int el = t >> 2;
    const int quad = t & 3;
    const int eM = w * 16 + m16;

    if (w == 0) {
        for (int f = 0; f < 18; ++f) {
            int nt = f / 3, kt = f - (f / 3) * 3;
            *(s16x8*)&sW2f[(f * 64 + lane) * 8] =
                *(const s16x8*)&W2Tb[(nt * 16 + m16) * 96 + kt * 32 + q * 8];
        }
    }
    s16x8 bfrC[6][2];
    #pragma unroll
    for (int nt = 0; nt < 6; ++nt)
        #pragma unroll
        for (int kt = 0; kt < 2; ++kt)
            bfrC[nt][kt] = *(const s16x8*)&W1cgT[(nt * 16 + m16) * 64 + kt * 32 + q * 8];
    float b2v[6];
    #pragma unroll
    for (int nt = 0; nt < 6; ++nt) b2v[nt] = b2[nt * 16 + m16];

    int b = blockIdx.x;
    int xcd = b & 7, bi = b >> 3;
    int c = (xcd < XR) ? (xcd * (XQ + 1) + bi)
                       : (XR * (XQ + 1) + (xcd - XR) * XQ + bi);
    const int tile0 = c * TPB_E;

    int2 edT1;
    s16x8 hvvT;
    float rcT, rsT;
    float gdT, gcgT, gsgT;
    {
        int2 edT = edges[tile0 * 64 + el];
        edT1 = edges[(tile0 + 1) * 64 + el];
        hvvT = *(const s16x8*)&SrcRec[edT.x * 128 + 96 + quad * 8];
        int sN = edT.x, dN = edT.y;
        float ca, sa, cb, sb;
        __sincosf(2.0f * ori[dN], &sa, &ca);
        __sincosf(2.0f * ori[sN], &sb, &cb);
        rcT = cb * ca + sb * sa;
        rsT = sb * ca - cb * sa;
        float dx = pos[2 * sN] - pos[2 * dN];
        float dy = pos[2 * sN + 1] - pos[2 * dN + 1];
        float d2 = dx * dx + dy * dy;
        gdT = sqrtf(d2) + 1e-6f;
        float c2f, s2f;
        if (d2 > 0.f) {
            float inv = __builtin_amdgcn_rcpf(d2);
            c2f = (dx * dx - dy * dy) * inv;
            s2f = 2.0f * dx * dy * inv;
        } else { c2f = 1.0f; s2f = 0.0f; }
        gcgT = c2f * ca + s2f * sa;
        gsgT = s2f * ca - c2f * sa;
        if (quad == 0) { s_srcM[0][el] = sN; s_dstM[0][el] = dN; }
    }
    __syncthreads();
    s16x8 pqP[3], pqQ[3];
    {
        int sN = s_srcM[0][eM], dN = s_dstM[0][eM];
        #pragma unroll
        for (int kt = 0; kt < 3; ++kt) {
            pqP[kt] = *(const s16x8*)&SrcRec[sN * 128 + kt * 32 + q * 8];
            pqQ[kt] = *(const s16x8*)&Qt[dN * 96 + kt * 32 + q * 8];
        }
    }

    int cur = 0;
    for (int tl = 0; tl < TPB_E; ++tl) {
        const int nx = cur ^ 1;
        const int tlN2 = (tl + 2 < TPB_E) ? tl + 2 : TPB_E - 1;

        {
            s16x8 rv;
            #pragma unroll
            for (int p2 = 0; p2 < 4; ++p2) {
                float x = bfbits2f(hvvT[2 * p2]), y = bfbits2f(hvvT[2 * p2 + 1]);
                rv[2 * p2]     = f2bfbits(rcT * x - rsT * y);
                rv[2 * p2 + 1] = f2bfbits(rsT * x + rcT * y);
            }
            *(s16x8*)&hVG[el][quad * 8] = rv;
            s16x8 up = (s16x8){0, 0, 0, 0, 0, 0, 0, 0};
            if (quad == 0) {
                up[0] = f2bfbits(gdT); up[1] = f2bfbits(gcgT); up[2] = f2bfbits(gsgT);
            }
            *(s16x8*)&hVG[el][32 + quad * 8] = up;
        }
        int2 edT2 = edges[(tile0 + tlN2) * 64 + el];
        s16x8 hvvN = *(const s16x8*)&SrcRec[edT1.x * 128 + 96 + quad * 8];
        {
            s16x8 afr0 = *(const s16x8*)&hVG[eM][q * 8];
            s16x8 afr1 = *(const s16x8*)&hVG[eM][32 + q * 8];
            #pragma unroll
            for (int nt = 0; nt < 6; ++nt) {
                f32x4 a1 = __builtin_amdgcn_mfma_f32_16x16x32_bf16(
                    afr0, bfrC[nt][0], (f32x4){0.f, 0.f, 0.f, 0.f}, 0, 0, 0);
                a1 = __builtin_amdgcn_mfma_f32_16x16x32_bf16(
                    afr1, bfrC[nt][1], a1, 0, 0, 0);
                int u = nt * 16 + m16;
                #pragma unroll
                for (int r = 0; r < 4; ++r)
                    s_vf[w * 16 + q * 4 + r][u] = f2bf(a1[r]);
            }
        }
        float rcN, rsN, gdN, gcgN, gsgN;
        {
            int sN = edT1.x, dN = edT1.y;
            float ca, sa, cb, sb;
            __sincosf(2.0f * ori[dN], &sa, &ca);
            __sincosf(2.0f * ori[sN], &sb, &cb);
            rcN = cb * ca + sb * sa;
            rsN = sb * ca - cb * sa;
            float dx = pos[2 * sN] - pos[2 * dN];
            float dy = pos[2 * sN + 1] - pos[2 * dN + 1];
            float d2 = dx * dx + dy * dy;
            gdN = sqrtf(d2) + 1e-6f;
            float c2f, s2f;
            if (d2 > 0.f) {
                float inv = __builtin_amdgcn_rcpf(d2);
                c2f = (dx * dx - dy * dy) * inv;
                s2f = 2.0f * dx * dy * inv;
            } else { c2f = 1.0f; s2f = 0.0f; }
            gcgN = c2f * ca + s2f * sa;
            gsgN = s2f * ca - c2f * sa;
            if (quad == 0) { s_srcM[nx][el] = sN; s_dstM[nx][el] = dN; }
        }

        s16x8 afr[3];
        #pragma unroll
        for (int kt = 0; kt < 3; ++kt) {
            int j = kt * 32 + q * 8;
            s16x8 Vv = *(const s16x8*)&s_vf[eM][j];
            s16x8 hb;
            #pragma unroll
            for (int k2 = 0; k2 < 8; ++k2) {
                float pre = bfbits2f(pqP[kt][k2]) + bfbits2f(pqQ[kt][k2])
                          + bfbits2f(Vv[k2]);
                float h = pre * __builtin_amdgcn_rcpf(1.0f + __expf(-pre));
                hb[k2] = f2bfbits(h);
            }
            afr[kt] = hb;
        }
        {
            int sN = s_srcM[nx][eM], dN = s_dstM[nx][eM];
            #pragma unroll
            for (int kt = 0; kt < 3; ++kt) {
                pqP[kt] = *(const s16x8*)&SrcRec[sN * 128 + kt * 32 + q * 8];
                pqQ[kt] = *(const s16x8*)&Qt[dN * 96 + kt * 32 + q * 8];
            }
        }
        {
            f32x4 acc[6];
            #pragma unroll
            for (int nt = 0; nt < 6; ++nt) acc[nt] = (f32x4){0.f, 0.f, 0.f, 0.f};
            #pragma unroll
            for (int nt = 0; nt < 6; ++nt)
                #pragma unroll
                for (int kt = 0; kt < 3; ++kt) {
                    s16x8 bf = *(const s16x8*)&sW2f[((nt * 3 + kt) * 64 + lane) * 8];
                    acc[nt] = __builtin_amdgcn_mfma_f32_16x16x32_bf16(
                        afr[kt], bf, acc[nt], 0, 0, 0);
                }
            #pragma unroll
            for (int nt = 0; nt < 6; ++nt) {
                int u = nt * 16 + m16;
                float bb = b2v[nt];
                #pragma unroll
                for (int r = 0; r < 4; ++r)
                    s_vf[w * 16 + q * 4 + r][u] = f2bf(acc[nt][r] + bb);
            }
        }
        __syncthreads();

        {
            int dl = s_dstM[cur][lane];
            int dp = (lane > 0) ? s_dstM[cur][lane - 1] : -1;
            bool bnd = (lane > 0) && (dl != dp);
            unsigned long long mask = __ballot(bnd);
            int nseg = (int)__popcll(mask) + 1;
            if (bnd) s_segstart[__popcll(mask & (~0ull >> (63 - lane)))] = lane;
            if (lane == 0) s_segstart[0] = 0;

            for (int idx = t; idx < nseg * HID; idx += 256) {
                int sg = idx / HID;
                int u = idx - sg * HID;
                int e0 = s_segstart[sg];
                int e1 = (sg + 1 < nseg) ? s_segstart[sg + 1] : 64;
                float sum = 0.f;
                for (int e = e0; e < e1; ++e) sum += bf2f(s_vf[e][u]);
                int dN = s_dstM[cur][e0];
                if (u < SDIM) atomicAdd(&out[dN * SDIM + u], sum);
                else atomicAdd(&out[N_NODESC * SDIM + dN * VDIM + (u - SDIM)], sum);
            }
        }

        edT1 = edT2; hvvT = hvvN;
        rcT = rcN; rsT = rsN; gdT = gdN; gcgT = gcgN; gsgT = gsgN;
        cur = nx;
        __syncthreads();
    }
}

// ---------------------------------------------------------------------------
// Mid/low-tier fallbacks (unchanged).
__global__ __launch_bounds__(128) void node_precompute(
    const float* __restrict__ hs, const float* __restrict__ hv,
    const float* __restrict__ W1, const float* __restrict__ b1,
    __hip_bfloat16* __restrict__ Pp, __hip_bfloat16* __restrict__ Qt,
    __hip_bfloat16* __restrict__ Ut, __hip_bfloat16* __restrict__ Vt) {
    int n = blockIdx.x;
    __shared__ float s_hs[SDIM];
    __shared__ float s_hv[VDIM];
    int t = threadIdx.x;
    if (t < 64) s_hs[t] = hs[n * SDIM + t];
    else if (t < 96) s_hv[t - 64] = hv[n * VDIM + (t - 64)];
    __syncthreads();
    if (t < HID) {
        float p = b1[t], qq = 0.f, u = 0.f, v = 0.f;
        for (int k = 0; k < 64; ++k) {
            float x = s_hs[k];
            p += x * W1[k * HID + t];
            qq += x * W1[(64 + k) * HID + t];
        }
        for (int pr = 0; pr < 16; ++pr) {
            float x = s_hv[2 * pr], y = s_hv[2 * pr + 1];
            float wa = W1[(128 + 2 * pr) * HID + t];
            float wb = W1[(128 + 2 * pr + 1) * HID + t];
            u += x * wa + y * wb;
            v += x * wb - y * wa;
        }
        Pp[n * HID + t] = f2bf(p);
        Qt[n * HID + t] = f2bf(qq);
        Ut[n * HID + t] = f2bf(u);
        Vt[n * HID + t] = f2bf(v);
    }
}

__global__ void init_out(const float* __restrict__ hs, const float* __restrict__ hv,
                         float* __restrict__ out) {
    int i = blockIdx.x * blockDim.x + threadIdx.x;
    if (i >= N_NODESC * (SDIM + VDIM)) return;
    out[i] = (i < N_NODESC * SDIM) ? hs[i] : hv[i - N_NODESC * SDIM];
}

__global__ void detect_kernel(const int* ei, int* flag) {
    if (blockIdx.x == 0 && threadIdx.x == 0) {
        int z = 1;
        for (int k = 0; k < 64; ++k) {
            if (ei[2 * k + 1] != 0) { z = 0; break; }
        }
        *flag = z;
    }
}

__global__ __launch_bounds__(256) void edge_kernel(
    const int* __restrict__ ei, const float* __restrict__ pos,
    const float* __restrict__ ori, const float* __restrict__ W1,
    const float* __restrict__ W2, const float* __restrict__ b2,
    const __hip_bfloat16* __restrict__ Pp, const __hip_bfloat16* __restrict__ Qt,
    const __hip_bfloat16* __restrict__ Ut, const __hip_bfloat16* __restrict__ Vt,
    const int* __restrict__ flag64, float* __restrict__ out) {
    __shared__ int s_src[64], s_dst[64];
    __shared__ float s_c[64], s_s[64], s_d[64], s_cg[64], s_sg[64];
    __shared__ float s_w1d[3][HID];
    __shared__ __hip_bfloat16 hA[64][104];
    __shared__ __hip_bfloat16 W2T[HID][104];

    const int t = threadIdx.x;
    const int lane = t & 63;
    const int w = t >> 6;
    const int m16 = lane & 15;
    const int q = lane >> 4;

    for (int idx = t; idx < HID * HID; idx += 256) {
        int k = idx / HID;
        int n = idx - k * HID;
        W2T[n][k] = f2bf(W2[idx]);
    }
    for (int idx = t; idx < 3 * HID; idx += 256) {
        int r = idx / HID, j = idx - r * HID;
        s_w1d[r][j] = W1[(160 + r) * HID + j];
    }
    __syncthreads();

    s16x8 bfr[6][3];
    for (int nt = 0; nt < 6; ++nt)
        for (int kt = 0; kt < 3; ++kt)
            bfr[nt][kt] = *(const s16x8*)&W2T[nt * 16 + m16][kt * 32 + q * 8];
    float b2v[6];
    for (int nt = 0; nt < 6; ++nt) b2v[nt] = b2[nt * 16 + m16];

    const bool i64 = (*flag64 != 0);
    const long long* ei64 = (const long long*)ei;

    for (int tile = blockIdx.x; tile < N_EDGESC / 64; tile += gridDim.x) {
        __syncthreads();

        if (t < 64) {
            int e = tile * 64 + t;
            int sN, dN;
            if (i64) { sN = (int)ei64[e]; dN = (int)ei64[N_EDGESC + e]; }
            else     { sN = ei[e];        dN = ei[N_EDGESC + e]; }
            s_src[t] = sN; s_dst[t] = dN;
            float ca, sa, cb, sb;
            __sincosf(2.0f * ori[dN], &sa, &ca);
            __sincosf(2.0f * ori[sN], &sb, &cb);
            s_c[t] = cb * ca + sb * sa;
            s_s[t] = sb * ca - cb * sa;
            float dx = pos[2 * sN] - pos[2 * dN];
            float dy = pos[2 * sN + 1] - pos[2 * dN + 1];
            float d2 = dx * dx + dy * dy;
            s_d[t] = sqrtf(d2) + 1e-6f;
            float c2f, s2f;
            if (d2 > 0.f) {
                float inv = 1.0f / d2;
                c2f = (dx * dx - dy * dy) * inv;
                s2f = 2.0f * dx * dy * inv;
            } else { c2f = 1.0f; s2f = 0.0f; }
            s_cg[t] = c2f * ca + s2f * sa;
            s_sg[t] = s2f * ca - c2f * sa;
        }
        __syncthreads();

        for (int p = 0; p < 24; ++p) {
            int idx = p * 256 + t;
            int e = idx / HID;
            int j = idx - e * HID;
            int sN = s_src[e], dN = s_dst[e];
            float pre = bf2f(Pp[sN * HID + j]) + bf2f(Qt[dN * HID + j])
                      + s_c[e] * bf2f(Ut[sN * HID + j])
                      + s_s[e] * bf2f(Vt[sN * HID + j])
                      + s_d[e] * s_w1d[0][j] + s_cg[e] * s_w1d[1][j]
                      + s_sg[e] * s_w1d[2][j];
            float h = pre / (1.0f + __expf(-pre));
            hA[e][j] = f2bf(h);
        }
        __syncthreads();

        f32x4 acc[6];
        for (int nt = 0; nt < 6; ++nt) acc[nt] = (f32x4){0.f, 0.f, 0.f, 0.f};
        s16x8 afr[3];
        for (int kt = 0; kt < 3; ++kt)
            afr[kt] = *(const s16x8*)&hA[w * 16 + m16][kt * 32 + q * 8];
        for (int nt = 0; nt < 6; ++nt)
            for (int kt = 0; kt < 3; ++kt)
                acc[nt] = __builtin_amdgcn_mfma_f32_16x16x32_bf16(
                    afr[kt], bfr[nt][kt], acc[nt], 0, 0, 0);

        for (int nt = 0; nt < 6; ++nt) {
            int u = nt * 16 + m16;
            for (int r = 0; r < 4; ++r) {
                int eloc = w * 16 + q * 4 + r;
                int dN = s_dst[eloc];
                float val = acc[nt][r] + b2v[nt];
                if (u < SDIM) atomicAdd(&out[dN * SDIM + u], val);
                else atomicAdd(&out[N_NODESC * SDIM + dN * VDIM + (u - SDIM)], val);
            }
        }
    }
}

__global__ __launch_bounds__(192) void edge_fallback(
    const int* __restrict__ ei, const float* __restrict__ hs,
    const float* __restrict__ hv, const float* __restrict__ pos,
    const float* __restrict__ ori, const float* __restrict__ W1,
    const float* __restrict__ b1, const float* __restrict__ W2,
    const float* __restrict__ b2, const int* __restrict__ flag64,
    float* __restrict__ out) {
    __shared__ float s_msg[IN_DIMC];
    __shared__ float s_h[HID];
    int e = blockIdx.x;
    int t = threadIdx.x;
    const bool i64 = (*flag64 != 0);
    int sN, dN;
    if (i64) {
        const long long* e64 = (const long long*)ei;
        sN = (int)e64[e]; dN = (int)e64[N_EDGESC + e];
    } else { sN = ei[e]; dN = ei[N_EDGESC + e]; }

    if (t < IN_DIMC) {
        if (t < 64) s_msg[t] = hs[sN * SDIM + t];
        else if (t < 128) s_msg[t] = hs[dN * SDIM + (t - 64)];
        else {
            float ca, sa, cb, sb;
            __sincosf(2.0f * ori[dN], &sa, &ca);
            __sincosf(2.0f * ori[sN], &sb, &cb);
            float c = cb * ca + sb * sa;
            float s = sb * ca - cb * sa;
            float dx = pos[2 * sN] - pos[2 * dN];
            float dy = pos[2 * sN + 1] - pos[2 * dN + 1];
            float d2 = dx * dx + dy * dy;
            if (t < 160) {
                int pr = (t - 128) >> 1;
                float x = hv[sN * VDIM + 2 * pr], y = hv[sN * VDIM + 2 * pr + 1];
                s_msg[t] = ((t & 1) == 0) ? (c * x - s * y) : (s * x + c * y);
            } else if (t == 160) s_msg[t] = sqrtf(d2) + 1e-6f;
            else {
                float c2f = 1.0f, s2f = 0.0f;
                if (d2 > 0.f) {
                    float inv = 1.0f / d2;
                    c2f = (dx * dx - dy * dy) * inv;
                    s2f = 2.0f * dx * dy * inv;
                }
                s_msg[t] = (t == 161) ? (c2f * ca + s2f * sa) : (s2f * ca - c2f * sa);
            }
        }
    }
    __syncthreads();
    if (t < HID) {
        float a = b1[t];
        for (int k = 0; k < IN_DIMC; ++k) a += s_msg[k] * W1[k * HID + t];
        s_h[t] = a / (1.0f + __expf(-a));
    }
    __syncthreads();
    if (t < HID) {
        float a = b2[t];
        for (int k = 0; k < HID; ++k) a += s_h[k] * W2[k * HID + t];
        if (t < SDIM) atomicAdd(&out[dN * SDIM + t], a);
        else atomicAdd(&out[N_NODESC * SDIM + dN * VDIM + (t - SDIM)], a);
    }
}

// ---------------------------------------------------------------------------
extern "C" void kernel_launch(void* const* d_in, const int* in_sizes, int n_in,
                              void* d_out, int out_size, void* d_ws, size_t ws_size,
                              hipStream_t stream) {
    const float* hs  = (const float*)d_in[0];
    const float* hv  = (const float*)d_in[1];
    const int*   ei  = (const int*)d_in[2];
    const float* pos = (const float*)d_in[3];
    const float* ori = (const float*)d_in[4];
    const float* W1  = (const float*)d_in[5];
    const float* b1  = (const float*)d_in[6];
    const float* W2  = (const float*)d_in[7];
    const float* b2  = (const float*)d_in[8];
    float* out = (float*)d_out;

    // sorted-tier workspace layout (256B-aligned chunks)
    const size_t SREC = (size_t)N_NODESC * 128 * sizeof(__hip_bfloat16);  // 12.8 MB
    const size_t QTB  = (size_t)N_NODESC * 96 * sizeof(__hip_bfloat16);   // 9.6 MB
    const size_t CNT  = ((size_t)N_NODESC * sizeof(int) + 255) & ~255ull; // 200 KB
    const size_t EDG  = (size_t)N_EDGESC * sizeof(int2);                  // 12.8 MB
    const size_t WBT2 = ((size_t)192 * 64 * 2 + 255) & ~255ull;
    const size_t W1CG = ((size_t)96 * 64 * 2 + 255) & ~255ull;
    const size_t W2TS = ((size_t)96 * 96 * 2 + 255) & ~255ull;
    const size_t FLG  = 256;
    const size_t BSM  = 1024;
    const size_t BOF  = 1024;
    const size_t CTR  = 256;
    const size_t SORT_WS = SREC + QTB + 2 * CNT + EDG + WBT2 + W1CG + W2TS
                         + FLG + BSM + BOF + CTR;

    const size_t TBL = (size_t)N_NODESC * HID * sizeof(__hip_bfloat16);   // 9.6 MB
    const bool big = ws_size >= 4 * TBL + 16;
    const bool srt = ws_size >= SORT_WS;

    if (srt) {
        char* ws = (char*)d_ws;
        __hip_bfloat16* SrcRec = (__hip_bfloat16*)(ws);
        __hip_bfloat16* Qt     = (__hip_bfloat16*)(ws + SREC);
        int* counts            = (int*)(ws + SREC + QTB);
        int* cur               = (int*)(ws + SREC + QTB + CNT);
        int2* edges            = (int2*)(ws + SREC + QTB + 2 * CNT);
        __hip_bfloat16* WbT2   = (__hip_bfloat16*)(ws + SREC + QTB + 2 * CNT + EDG);
        __hip_bfloat16* W1cgT  = (__hip_bfloat16*)(ws + SREC + QTB + 2 * CNT + EDG + WBT2);
        __hip_bfloat16* W2Tb   = (__hip_bfloat16*)(ws + SREC + QTB + 2 * CNT + EDG + WBT2 + W1CG);
        char* tail             = ws + SREC + QTB + 2 * CNT + EDG + WBT2 + W1CG + W2TS;
        int* flag              = (int*)(tail);
        int* bsum              = (int*)(tail + FLG);
        int* boff              = (int*)(tail + FLG + BSM);
        int* ctrp              = (int*)(tail + FLG + BSM + BOF);

        // Host-side int64 detect from byte size (ambiguous -> in-kernel detect).
        int hostflag = -1;
        long long eib = (long long)in_sizes[2];
        if (eib == 2ll * N_EDGESC * 8) hostflag = 1;
        else if (eib == 2ll * N_EDGESC * 4) hostflag = 0;

        int occ = 0;
        hipError_t qerr = hipOccupancyMaxActiveBlocksPerMultiprocessor(
            &occ, mega_aux, 256, 0);
        hipError_t lerr = hipErrorUnknown;
        if (qerr == hipSuccess && occ >= 1) {
            int G = occ * 256;            // 256 CUs on MI355X
            if (G > 1024) G = 1024;
            if (G < 256) G = 256;
            void* args[] = {
                (void*)&ei, (void*)&hostflag, (void*)&hs, (void*)&hv,
                (void*)&W1, (void*)&W2, (void*)&b1, (void*)&out,
                (void*)&counts, (void*)&cur, (void*)&edges,
                (void*)&SrcRec, (void*)&Qt, (void*)&WbT2, (void*)&W1cgT,
                (void*)&W2Tb, (void*)&flag, (void*)&bsum, (void*)&boff,
                (void*)&ctrp };
            lerr = hipLaunchCooperativeKernel((void*)mega_aux, dim3(G), dim3(256),
                                              args, 0, stream);
        }
        if (lerr != hipSuccess) {
            // Fallback: proven round-9 launch sequence.
            detect_zero<<<(N_NODESC + 255) / 256, 256, 0, stream>>>(ei, flag, counts);
            fused_init<<<N_EDGESC / 256, 256, 0, stream>>>(
                hs, hv, out, counts, W1, W2, SrcRec, WbT2, W1cgT, W2Tb, ei, flag);
            scan_partials<<<SCB, 256, 0, stream>>>(counts, cur, bsum);
            scan_bsums<<<1, 256, 0, stream>>>(bsum, boff);
            scan_apply<<<SCB, 256, 0, stream>>>(cur, boff);
            scatter_precompute<<<NPRE + N_EDGESC / 256, 256, 0, stream>>>(
                ei, flag, cur, edges, hs, WbT2, b1, SrcRec, Qt);
        }
        edge_kernel_sorted<<<GRID_E, 256, 0, stream>>>(edges, pos, ori, W2Tb, b2,
                                                       SrcRec, Qt, W1cgT, out);
    } else if (big) {
        char* ws = (char*)d_ws;
        __hip_bfloat16* Pp = (__hip_bfloat16*)(ws);
        __hip_bfloat16* Qt = (__hip_bfloat16*)(ws + TBL);
        __hip_bfloat16* Ut = (__hip_bfloat16*)(ws + 2 * TBL);
        __hip_bfloat16* Vt = (__hip_bfloat16*)(ws + 3 * TBL);
        int* flag = (int*)(ws + 4 * TBL);
        init_out<<<(N_NODESC * (SDIM + VDIM) + 255) / 256, 256, 0, stream>>>(hs, hv, out);
        detect_kernel<<<1, 64, 0, stream>>>(ei, flag);
        node_precompute<<<N_NODESC, 128, 0, stream>>>(hs, hv, W1, b1, Pp, Qt, Ut, Vt);
        edge_kernel<<<2500, 256, 0, stream>>>(ei, pos, ori, W1, W2, b2,
                                              Pp, Qt, Ut, Vt, flag, out);
    } else {
        int* flag = (int*)d_ws;
        init_out<<<(N_NODESC * (SDIM + VDIM) + 255) / 256, 256, 0, stream>>>(hs, hv, out);
        detect_kernel<<<1, 64, 0, stream>>>(ei, flag);
        edge_fallback<<<N_EDGESC, 192, 0, stream>>>(ei, hs, hv, pos, ori, W1, b1,
                                                    W2, b2, flag, out);
    }
}

// Round 11
// 489.161 us; speedup vs baseline: 1.9397x; 1.9397x over previous
//
#include <hip/hip_runtime.h>
#include <hip/hip_bf16.h>

#define N_NODESC 50000
#define N_EDGESC 1600000
#define SDIM 64
#define VDIM 32
#define HID 96
#define IN_DIMC 163

#define GRID_E 6250
#define TPB_E 4            // tiles per block (25000 tiles / 6250 blocks)
#define NXCD 8
#define XQ (GRID_E / NXCD) // 781
#define XR (GRID_E % NXCD) // 2
#define NPRE 782           // precompute chunks (50000/64 rounded up)
#define SCB 196            // scan blocks (50000 / 256 rounded up)

typedef float f32x4 __attribute__((ext_vector_type(4)));
typedef short s16x8 __attribute__((ext_vector_type(8)));

__device__ __forceinline__ float bf2f(__hip_bfloat16 x) { return __bfloat162float(x); }
__device__ __forceinline__ __hip_bfloat16 f2bf(float x) { return __float2bfloat16(x); }
__device__ __forceinline__ float bfbits2f(short b) {
    unsigned u = ((unsigned)(unsigned short)b) << 16;
    return __builtin_bit_cast(float, u);
}
__device__ __forceinline__ short f2bfbits(float x) {
    __hip_bfloat16 h = __float2bfloat16(x);
    return *(const short*)&h;
}

// ---------------------------------------------------------------------------
// L1: weight packs + counts/desc zero + int64-layout detect. All independent
// of everything else, so they run first in one small launch (196 blocks).
__global__ __launch_bounds__(256) void prep_kernel(
    const int* __restrict__ ei, int hostflag, int* __restrict__ flagp,
    const float* __restrict__ W1, const float* __restrict__ W2,
    __hip_bfloat16* __restrict__ WbT2, __hip_bfloat16* __restrict__ W1cgT,
    __hip_bfloat16* __restrict__ W2Tb,
    int* __restrict__ counts, int* __restrict__ desc) {
    int i = blockIdx.x * blockDim.x + threadIdx.x;
    if (i < N_NODESC) counts[i] = 0;
    if (i < SCB) desc[i] = 0;
    // WbT2 [192][64]: rows 0-95 = W1a^T (P), 96-191 = W1b^T (Q)
    if (i < 192 * 64) {
        int n = i >> 6, k = i & 63;
        float val = (n < 96) ? W1[k * HID + n] : W1[(64 + k) * HID + (n - 96)];
        WbT2[i] = f2bf(val);
    }
    // W1cgT [96][64]: cols 0-31 = W1c^T, 32-34 = geo rows, rest 0
    if (i < 96 * 64) {
        int n = i >> 6, k = i & 63;
        float val = 0.f;
        if (k < 32) val = W1[(128 + k) * HID + n];
        else if (k < 35) val = W1[(160 + (k - 32)) * HID + n];
        W1cgT[i] = f2bf(val);
    }
    // W2Tb [96][96] = W2^T
    if (i < 96 * 96) {
        int n = i / 96, k = i - (i / 96) * 96;
        W2Tb[i] = f2bf(W2[k * HID + n]);
    }
    if (i == 0) {
        if (hostflag >= 0) *flagp = hostflag;
        else {
            int z = 1;
            for (int k = 0; k < 64; ++k) if (ei[2 * k + 1] != 0) { z = 0; break; }
            *flagp = z;
        }
    }
}

// ---------------------------------------------------------------------------
// MFMA node-precompute chunk (64 nodes): [P|Q] = hs_bf16 @ [W1a|W1b];
// P (+b1) -> SrcRec[n][0:96), Q -> Qt. LDS-staged, coalesced stores.
__device__ __forceinline__ void precompute_chunk(
    int ch, int t, const float* __restrict__ hs,
    const __hip_bfloat16* __restrict__ WbT2, const float* __restrict__ b1,
    __hip_bfloat16* __restrict__ SrcRec, __hip_bfloat16* __restrict__ Qt,
    __hip_bfloat16 (*sA)[72], __hip_bfloat16 (*sOut)[200]) {
    const int lane = t & 63;
    const int w = t >> 6;
    const int m16 = lane & 15;
    const int q = lane >> 4;
    const int nb = ch * 64;

    for (int idx = t; idx < 64 * 64; idx += 256) {
        int node = idx >> 6, f = idx & 63;
        int g = nb + node;
        sA[node][f] = f2bf(g < N_NODESC ? hs[g * SDIM + f] : 0.f);
    }
    __syncthreads();

    s16x8 bfr[3][2];
    float b1v[3];
    for (int nt = 0; nt < 3; ++nt) {
        int n_out = w * 48 + nt * 16 + m16;
        for (int kt = 0; kt < 2; ++kt)
            bfr[nt][kt] = *(const s16x8*)&WbT2[n_out * 64 + kt * 32 + q * 8];
        b1v[nt] = (n_out < 96) ? b1[n_out] : 0.f;
    }

    for (int ms = 0; ms < 4; ++ms) {
        s16x8 afr[2];
        for (int kt = 0; kt < 2; ++kt)
            afr[kt] = *(const s16x8*)&sA[ms * 16 + m16][kt * 32 + q * 8];
        f32x4 acc[3];
        for (int nt = 0; nt < 3; ++nt) acc[nt] = (f32x4){0.f, 0.f, 0.f, 0.f};
        for (int nt = 0; nt < 3; ++nt)
            for (int kt = 0; kt < 2; ++kt)
                acc[nt] = __builtin_amdgcn_mfma_f32_16x16x32_bf16(
                    afr[kt], bfr[nt][kt], acc[nt], 0, 0, 0);
        for (int nt = 0; nt < 3; ++nt) {
            int n_out = w * 48 + nt * 16 + m16;
            for (int r = 0; r < 4; ++r)
                sOut[ms * 16 + q * 4 + r][n_out] = f2bf(acc[nt][r] + b1v[nt]);
        }
    }
    __syncthreads();

    for (int idx = t; idx < 64 * 12; idx += 256) {
        int node = idx / 12, c2 = idx - (idx / 12) * 12;
        int g = nb + node;
        if (g < N_NODESC)
            *(s16x8*)&SrcRec[g * 128 + c2 * 8] = *(const s16x8*)&sOut[node][c2 * 8];
    }
    for (int idx = t; idx < 64 * 12; idx += 256) {
        int node = idx / 12, c2 = idx - (idx / 12) * 12;
        int g = nb + node;
        if (g < N_NODESC)
            *(s16x8*)&Qt[g * 96 + c2 * 8] = *(const s16x8*)&sOut[node][96 + c2 * 8];
    }
}

// ---------------------------------------------------------------------------
// L2: heterogeneous roles — blocks [0,NPRE) run the MFMA precompute (needs
// only WbT2 from L1); blocks [NPRE, NPRE+6250) do out-init + SrcRec.hv +
// dst histogram (one edge per thread). Overlaps MFMA-bound and
// memory/atomic-bound work in one launch.
__global__ __launch_bounds__(256, 2) void init_hist_precompute(
    const float* __restrict__ hs, const float* __restrict__ hv,
    float* __restrict__ out, int* __restrict__ counts,
    const int* __restrict__ ei, const int* __restrict__ flag64,
    const __hip_bfloat16* __restrict__ WbT2, const float* __restrict__ b1,
    __hip_bfloat16* __restrict__ SrcRec, __hip_bfloat16* __restrict__ Qt) {
    __shared__ __hip_bfloat16 sA[64][72];
    __shared__ __hip_bfloat16 sOut[64][200];
    const int blk = blockIdx.x;
    const int t = threadIdx.x;

    if (blk < NPRE) {
        precompute_chunk(blk, t, hs, WbT2, b1, SrcRec, Qt, sA, sOut);
        return;
    }
    const int e = (blk - NPRE) * 256 + t;   // exactly covers N_EDGESC

    // out = residual, float4-wide (1.2M items over 1.6M threads)
    if (e < N_NODESC * (SDIM + VDIM) / 4) {
        const int HS4 = N_NODESC * SDIM / 4;
        float4 v = (e < HS4) ? ((const float4*)hs)[e] : ((const float4*)hv)[e - HS4];
        ((float4*)out)[e] = v;
    }
    // SrcRec[n][96..128) = bf16(hv[n]), 8 elems/thread (200K items)
    if (e < N_NODESC * VDIM / 8) {
        int n = e >> 2, c = e & 3;
        const float4* hv4 = (const float4*)hv;
        float4 a = hv4[n * 8 + c * 2];
        float4 bq = hv4[n * 8 + c * 2 + 1];
        s16x8 o;
        o[0] = f2bfbits(a.x);  o[1] = f2bfbits(a.y);
        o[2] = f2bfbits(a.z);  o[3] = f2bfbits(a.w);
        o[4] = f2bfbits(bq.x); o[5] = f2bfbits(bq.y);
        o[6] = f2bfbits(bq.z); o[7] = f2bfbits(bq.w);
        *(s16x8*)&SrcRec[n * 128 + 96 + c * 8] = o;
    }
    // dst histogram
    {
        int dN;
        if (*flag64) dN = (int)((const long long*)ei)[N_EDGESC + e];
        else dN = ei[N_EDGESC + e];
        atomicAdd(&counts[dN], 1);
    }
}

// ---------------------------------------------------------------------------
// L3: single-pass decoupled-lookback exclusive scan (196 blocks, all
// co-resident on 256 CUs so the lookback spin is deadlock-free).
// desc[blk] packs {value<<2 | status}: 1 = aggregate ready, 2 = inclusive
// prefix ready. Value ≤ 1.6M so <<2 fits int. Single-word publish means
// no separate fence is needed.
__global__ __launch_bounds__(256) void scan_onepass(
    const int* __restrict__ counts, int* __restrict__ cur, int* __restrict__ desc) {
    __shared__ int sc[256];
    __shared__ int s_excl;
    const int blk = blockIdx.x, t = threadIdx.x;
    const int i = blk * 256 + t;
    int val = (i < N_NODESC) ? counts[i] : 0;
    sc[t] = val;
    __syncthreads();
    for (int d = 1; d < 256; d <<= 1) {
        int v = (t >= d) ? sc[t - d] : 0;
        __syncthreads();
        sc[t] += v;
        __syncthreads();
    }
    int aggregate = sc[255];
    if (t == 0) {
        if (blk == 0) {
            atomicExch(&desc[0], (aggregate << 2) | 2);
            s_excl = 0;
        } else {
            atomicExch(&desc[blk], (aggregate << 2) | 1);
            int excl = 0;
            int j = blk - 1;
            for (;;) {
                int d = atomicAdd(&desc[j], 0);   // device-scope atomic load
                int st = d & 3;
                if (st == 2) { excl += (d >> 2); break; }
                if (st == 1) { excl += (d >> 2); --j; }
            }
            atomicExch(&desc[blk], ((excl + aggregate) << 2) | 2);
            s_excl = excl;
        }
    }
    __syncthreads();
    if (i < N_NODESC) cur[i] = s_excl + sc[t] - val;
}

// ---------------------------------------------------------------------------
// L4: scatter edges into dst-sorted order.
__global__ __launch_bounds__(256) void scatter_kernel(
    const int* __restrict__ ei, const int* __restrict__ flag64,
    int* __restrict__ cur, int2* __restrict__ edges) {
    int e = blockIdx.x * blockDim.x + threadIdx.x;
    if (e >= N_EDGESC) return;
    int sN, dN;
    if (*flag64) {
        const long long* e64 = (const long long*)ei;
        sN = (int)e64[e]; dN = (int)e64[N_EDGESC + e];
    } else { sN = ei[e]; dN = ei[N_EDGESC + e]; }
    int p = atomicAdd(&cur[dN], 1);
    edges[p] = make_int2(sN, dN);
}

// ---------------------------------------------------------------------------
// Main edge kernel (unchanged; proven 217 µs config).
__global__ __launch_bounds__(256, 3) void edge_kernel_sorted(
    const int2* __restrict__ edges,
    const float* __restrict__ pos, const float* __restrict__ ori,
    const __hip_bfloat16* __restrict__ W2Tb, const float* __restrict__ b2,
    const __hip_bfloat16* __restrict__ SrcRec, const __hip_bfloat16* __restrict__ Qt,
    const __hip_bfloat16* __restrict__ W1cgT,
    float* __restrict__ out) {
    __shared__ int s_srcM[2][64], s_dstM[2][64];
    __shared__ alignas(16) __hip_bfloat16 hVG[64][72];    // [0:32) rot-hv, [32:64) geo
    __shared__ alignas(16) __hip_bfloat16 s_vf[64][104];  // vec+geo contrib / msg
    __shared__ alignas(16) short sW2f[18 * 64 * 8];       // W2 frags, lane-packed
    __shared__ int s_segstart[66];

    const int t = threadIdx.x;
    const int lane = t & 63;
    const int w = t >> 6;
    const int m16 = lane & 15;
    const int q = lane >> 4;
    const int el = t >> 2;
    const int quad = t & 3;
    const int eM = w * 16 + m16;

    if (w == 0) {
        for (int f = 0; f < 18; ++f) {
            int nt = f / 3, kt = f - (f / 3) * 3;
            *(s16x8*)&sW2f[(f * 64 + lane) * 8] =
                *(const s16x8*)&W2Tb[(nt * 16 + m16) * 96 + kt * 32 + q * 8];
        }
    }
    s16x8 bfrC[6][2];
    #pragma unroll
    for (int nt = 0; nt < 6; ++nt)
        #pragma unroll
        for (int kt = 0; kt < 2; ++kt)
            bfrC[nt][kt] = *(const s16x8*)&W1cgT[(nt * 16 + m16) * 64 + kt * 32 + q * 8];
    float b2v[6];
    #pragma unroll
    for (int nt = 0; nt < 6; ++nt) b2v[nt] = b2[nt * 16 + m16];

    int b = blockIdx.x;
    int xcd = b & 7, bi = b >> 3;
    int c = (xcd < XR) ? (xcd * (XQ + 1) + bi)
                       : (XR * (XQ + 1) + (xcd - XR) * XQ + bi);
    const int tile0 = c * TPB_E;

    int2 edT1;
    s16x8 hvvT;
    float rcT, rsT;
    float gdT, gcgT, gsgT;
    {
        int2 edT = edges[tile0 * 64 + el];
        edT1 = edges[(tile0 + 1) * 64 + el];
        hvvT = *(const s16x8*)&SrcRec[edT.x * 128 + 96 + quad * 8];
        int sN = edT.x, dN = edT.y;
        float ca, sa, cb, sb;
        __sincosf(2.0f * ori[dN], &sa, &ca);
        __sincosf(2.0f * ori[sN], &sb, &cb);
        rcT = cb * ca + sb * sa;
        rsT = sb * ca - cb * sa;
        float dx = pos[2 * sN] - pos[2 * dN];
        float dy = pos[2 * sN + 1] - pos[2 * dN + 1];
        float d2 = dx * dx + dy * dy;
        gdT = sqrtf(d2) + 1e-6f;
        float c2f, s2f;
        if (d2 > 0.f) {
            float inv = __builtin_amdgcn_rcpf(d2);
            c2f = (dx * dx - dy * dy) * inv;
            s2f = 2.0f * dx * dy * inv;
        } else { c2f = 1.0f; s2f = 0.0f; }
        gcgT = c2f * ca + s2f * sa;
        gsgT = s2f * ca - c2f * sa;
        if (quad == 0) { s_srcM[0][el] = sN; s_dstM[0][el] = dN; }
    }
    __syncthreads();
    s16x8 pqP[3], pqQ[3];
    {
        int sN = s_srcM[0][eM], dN = s_dstM[0][eM];
        #pragma unroll
        for (int kt = 0; kt < 3; ++kt) {
            pqP[kt] = *(const s16x8*)&SrcRec[sN * 128 + kt * 32 + q * 8];
            pqQ[kt] = *(const s16x8*)&Qt[dN * 96 + kt * 32 + q * 8];
        }
    }

    int cur = 0;
    for (int tl = 0; tl < TPB_E; ++tl) {
        const int nx = cur ^ 1;
        const int tlN2 = (tl + 2 < TPB_E) ? tl + 2 : TPB_E - 1;

        {
            s16x8 rv;
            #pragma unroll
            for (int p2 = 0; p2 < 4; ++p2) {
                float x = bfbits2f(hvvT[2 * p2]), y = bfbits2f(hvvT[2 * p2 + 1]);
                rv[2 * p2]     = f2bfbits(rcT * x - rsT * y);
                rv[2 * p2 + 1] = f2bfbits(rsT * x + rcT * y);
            }
            *(s16x8*)&hVG[el][quad * 8] = rv;
            s16x8 up = (s16x8){0, 0, 0, 0, 0, 0, 0, 0};
            if (quad == 0) {
                up[0] = f2bfbits(gdT); up[1] = f2bfbits(gcgT); up[2] = f2bfbits(gsgT);
            }
            *(s16x8*)&hVG[el][32 + quad * 8] = up;
        }
        int2 edT2 = edges[(tile0 + tlN2) * 64 + el];
        s16x8 hvvN = *(const s16x8*)&SrcRec[edT1.x * 128 + 96 + quad * 8];
        {
            s16x8 afr0 = *(const s16x8*)&hVG[eM][q * 8];
            s16x8 afr1 = *(const s16x8*)&hVG[eM][32 + q * 8];
            #pragma unroll
            for (int nt = 0; nt < 6; ++nt) {
                f32x4 a1 = __builtin_amdgcn_mfma_f32_16x16x32_bf16(
                    afr0, bfrC[nt][0], (f32x4){0.f, 0.f, 0.f, 0.f}, 0, 0, 0);
                a1 = __builtin_amdgcn_mfma_f32_16x16x32_bf16(
                    afr1, bfrC[nt][1], a1, 0, 0, 0);
                int u = nt * 16 + m16;
                #pragma unroll
                for (int r = 0; r < 4; ++r)
                    s_vf[w * 16 + q * 4 + r][u] = f2bf(a1[r]);
            }
        }
        float rcN, rsN, gdN, gcgN, gsgN;
        {
            int sN = edT1.x, dN = edT1.y;
            float ca, sa, cb, sb;
            __sincosf(2.0f * ori[dN], &sa, &ca);
            __sincosf(2.0f * ori[sN], &sb, &cb);
            rcN = cb * ca + sb * sa;
            rsN = sb * ca - cb * sa;
            float dx = pos[2 * sN] - pos[2 * dN];
            float dy = pos[2 * sN + 1] - pos[2 * dN + 1];
            float d2 = dx * dx + dy * dy;
            gdN = sqrtf(d2) + 1e-6f;
            float c2f, s2f;
            if (d2 > 0.f) {
                float inv = __builtin_amdgcn_rcpf(d2);
                c2f = (dx * dx - dy * dy) * inv;
                s2f = 2.0f * dx * dy * inv;
            } else { c2f = 1.0f; s2f = 0.0f; }
            gcgN = c2f * ca + s2f * sa;
            gsgN = s2f * ca - c2f * sa;
            if (quad == 0) { s_srcM[nx][el] = sN; s_dstM[nx][el] = dN; }
        }

        s16x8 afr[3];
        #pragma unroll
        for (int kt = 0; kt < 3; ++kt) {
            int j = kt * 32 + q * 8;
            s16x8 Vv = *(const s16x8*)&s_vf[eM][j];
            s16x8 hb;
            #pragma unroll
            for (int k2 = 0; k2 < 8; ++k2) {
                float pre = bfbits2f(pqP[kt][k2]) + bfbits2f(pqQ[kt][k2])
                          + bfbits2f(Vv[k2]);
                float h = pre * __builtin_amdgcn_rcpf(1.0f + __expf(-pre));
                hb[k2] = f2bfbits(h);
            }
            afr[kt] = hb;
        }
        {
            int sN = s_srcM[nx][eM], dN = s_dstM[nx][eM];
            #pragma unroll
            for (int kt = 0; kt < 3; ++kt) {
                pqP[kt] = *(const s16x8*)&SrcRec[sN * 128 + kt * 32 + q * 8];
                pqQ[kt] = *(const s16x8*)&Qt[dN * 96 + kt * 32 + q * 8];
            }
        }
        {
            f32x4 acc[6];
            #pragma unroll
            for (int nt = 0; nt < 6; ++nt) acc[nt] = (f32x4){0.f, 0.f, 0.f, 0.f};
            #pragma unroll
            for (int nt = 0; nt < 6; ++nt)
                #pragma unroll
                for (int kt = 0; kt < 3; ++kt) {
                    s16x8 bf = *(const s16x8*)&sW2f[((nt * 3 + kt) * 64 + lane) * 8];
                    acc[nt] = __builtin_amdgcn_mfma_f32_16x16x32_bf16(
                        afr[kt], bf, acc[nt], 0, 0, 0);
                }
            #pragma unroll
            for (int nt = 0; nt < 6; ++nt) {
                int u = nt * 16 + m16;
                float bb = b2v[nt];
                #pragma unroll
                for (int r = 0; r < 4; ++r)
                    s_vf[w * 16 + q * 4 + r][u] = f2bf(acc[nt][r] + bb);
            }
        }
        __syncthreads();

        {
            int dl = s_dstM[cur][lane];
            int dp = (lane > 0) ? s_dstM[cur][lane - 1] : -1;
            bool bnd = (lane > 0) && (dl != dp);
            unsigned long long mask = __ballot(bnd);
            int nseg = (int)__popcll(mask) + 1;
            if (bnd) s_segstart[__popcll(mask & (~0ull >> (63 - lane)))] = lane;
            if (lane == 0) s_segstart[0] = 0;

            for (int idx = t; idx < nseg * HID; idx += 256) {
                int sg = idx / HID;
                int u = idx - sg * HID;
                int e0 = s_segstart[sg];
                int e1 = (sg + 1 < nseg) ? s_segstart[sg + 1] : 64;
                float sum = 0.f;
                for (int e = e0; e < e1; ++e) sum += bf2f(s_vf[e][u]);
                int dN = s_dstM[cur][e0];
                if (u < SDIM) atomicAdd(&out[dN * SDIM + u], sum);
                else atomicAdd(&out[N_NODESC * SDIM + dN * VDIM + (u - SDIM)], sum);
            }
        }

        edT1 = edT2; hvvT = hvvN;
        rcT = rcN; rsT = rsN; gdT = gdN; gcgT = gcgN; gsgT = gsgN;
        cur = nx;
        __syncthreads();
    }
}

// ---------------------------------------------------------------------------
// Mid/low-tier fallbacks (unchanged).
__global__ __launch_bounds__(128) void node_precompute(
    const float* __restrict__ hs, const float* __restrict__ hv,
    const float* __restrict__ W1, const float* __restrict__ b1,
    __hip_bfloat16* __restrict__ Pp, __hip_bfloat16* __restrict__ Qt,
    __hip_bfloat16* __restrict__ Ut, __hip_bfloat16* __restrict__ Vt) {
    int n = blockIdx.x;
    __shared__ float s_hs[SDIM];
    __shared__ float s_hv[VDIM];
    int t = threadIdx.x;
    if (t < 64) s_hs[t] = hs[n * SDIM + t];
    else if (t < 96) s_hv[t - 64] = hv[n * VDIM + (t - 64)];
    __syncthreads();
    if (t < HID) {
        float p = b1[t], qq = 0.f, u = 0.f, v = 0.f;
        for (int k = 0; k < 64; ++k) {
            float x = s_hs[k];
            p += x * W1[k * HID + t];
            qq += x * W1[(64 + k) * HID + t];
        }
        for (int pr = 0; pr < 16; ++pr) {
            float x = s_hv[2 * pr], y = s_hv[2 * pr + 1];
            float wa = W1[(128 + 2 * pr) * HID + t];
            float wb = W1[(128 + 2 * pr + 1) * HID + t];
            u += x * wa + y * wb;
            v += x * wb - y * wa;
        }
        Pp[n * HID + t] = f2bf(p);
        Qt[n * HID + t] = f2bf(qq);
        Ut[n * HID + t] = f2bf(u);
        Vt[n * HID + t] = f2bf(v);
    }
}

__global__ void init_out(const float* __restrict__ hs, const float* __restrict__ hv,
                         float* __restrict__ out) {
    int i = blockIdx.x * blockDim.x + threadIdx.x;
    if (i >= N_NODESC * (SDIM + VDIM)) return;
    out[i] = (i < N_NODESC * SDIM) ? hs[i] : hv[i - N_NODESC * SDIM];
}

__global__ void detect_kernel(const int* ei, int* flag) {
    if (blockIdx.x == 0 && threadIdx.x == 0) {
        int z = 1;
        for (int k = 0; k < 64; ++k) {
            if (ei[2 * k + 1] != 0) { z = 0; break; }
        }
        *flag = z;
    }
}

__global__ __launch_bounds__(256) void edge_kernel(
    const int* __restrict__ ei, const float* __restrict__ pos,
    const float* __restrict__ ori, const float* __restrict__ W1,
    const float* __restrict__ W2, const float* __restrict__ b2,
    const __hip_bfloat16* __restrict__ Pp, const __hip_bfloat16* __restrict__ Qt,
    const __hip_bfloat16* __restrict__ Ut, const __hip_bfloat16* __restrict__ Vt,
    const int* __restrict__ flag64, float* __restrict__ out) {
    __shared__ int s_src[64], s_dst[64];
    __shared__ float s_c[64], s_s[64], s_d[64], s_cg[64], s_sg[64];
    __shared__ float s_w1d[3][HID];
    __shared__ __hip_bfloat16 hA[64][104];
    __shared__ __hip_bfloat16 W2T[HID][104];

    const int t = threadIdx.x;
    const int lane = t & 63;
    const int w = t >> 6;
    const int m16 = lane & 15;
    const int q = lane >> 4;

    for (int idx = t; idx < HID * HID; idx += 256) {
        int k = idx / HID;
        int n = idx - k * HID;
        W2T[n][k] = f2bf(W2[idx]);
    }
    for (int idx = t; idx < 3 * HID; idx += 256) {
        int r = idx / HID, j = idx - r * HID;
        s_w1d[r][j] = W1[(160 + r) * HID + j];
    }
    __syncthreads();

    s16x8 bfr[6][3];
    for (int nt = 0; nt < 6; ++nt)
        for (int kt = 0; kt < 3; ++kt)
            bfr[nt][kt] = *(const s16x8*)&W2T[nt * 16 + m16][kt * 32 + q * 8];
    float b2v[6];
    for (int nt = 0; nt < 6; ++nt) b2v[nt] = b2[nt * 16 + m16];

    const bool i64 = (*flag64 != 0);
    const long long* ei64 = (const long long*)ei;

    for (int tile = blockIdx.x; tile < N_EDGESC / 64; tile += gridDim.x) {
        __syncthreads();

        if (t < 64) {
            int e = tile * 64 + t;
            int sN, dN;
            if (i64) { sN = (int)ei64[e]; dN = (int)ei64[N_EDGESC + e]; }
            else     { sN = ei[e];        dN = ei[N_EDGESC + e]; }
            s_src[t] = sN; s_dst[t] = dN;
            float ca, sa, cb, sb;
            __sincosf(2.0f * ori[dN], &sa, &ca);
            __sincosf(2.0f * ori[sN], &sb, &cb);
            s_c[t] = cb * ca + sb * sa;
            s_s[t] = sb * ca - cb * sa;
            float dx = pos[2 * sN] - pos[2 * dN];
            float dy = pos[2 * sN + 1] - pos[2 * dN + 1];
            float d2 = dx * dx + dy * dy;
            s_d[t] = sqrtf(d2) + 1e-6f;
            float c2f, s2f;
            if (d2 > 0.f) {
                float inv = 1.0f / d2;
                c2f = (dx * dx - dy * dy) * inv;
                s2f = 2.0f * dx * dy * inv;
            } else { c2f = 1.0f; s2f = 0.0f; }
            s_cg[t] = c2f * ca + s2f * sa;
            s_sg[t] = s2f * ca - c2f * sa;
        }
        __syncthreads();

        for (int p = 0; p < 24; ++p) {
            int idx = p * 256 + t;
            int e = idx / HID;
            int j = idx - e * HID;
            int sN = s_src[e], dN = s_dst[e];
            float pre = bf2f(Pp[sN * HID + j]) + bf2f(Qt[dN * HID + j])
                      + s_c[e] * bf2f(Ut[sN * HID + j])
                      + s_s[e] * bf2f(Vt[sN * HID + j])
                      + s_d[e] * s_w1d[0][j] + s_cg[e] * s_w1d[1][j]
                      + s_sg[e] * s_w1d[2][j];
            float h = pre / (1.0f + __expf(-pre));
            hA[e][j] = f2bf(h);
        }
        __syncthreads();

        f32x4 acc[6];
        for (int nt = 0; nt < 6; ++nt) acc[nt] = (f32x4){0.f, 0.f, 0.f, 0.f};
        s16x8 afr[3];
        for (int kt = 0; kt < 3; ++kt)
            afr[kt] = *(const s16x8*)&hA[w * 16 + m16][kt * 32 + q * 8];
        for (int nt = 0; nt < 6; ++nt)
            for (int kt = 0; kt < 3; ++kt)
                acc[nt] = __builtin_amdgcn_mfma_f32_16x16x32_bf16(
                    afr[kt], bfr[nt][kt], acc[nt], 0, 0, 0);

        for (int nt = 0; nt < 6; ++nt) {
            int u = nt * 16 + m16;
            for (int r = 0; r < 4; ++r) {
                int eloc = w * 16 + q * 4 + r;
                int dN = s_dst[eloc];
                float val = acc[nt][r] + b2v[nt];
                if (u < SDIM) atomicAdd(&out[dN * SDIM + u], val);
                else atomicAdd(&out[N_NODESC * SDIM + dN * VDIM + (u - SDIM)], val);
            }
        }
    }
}

__global__ __launch_bounds__(192) void edge_fallback(
    const int* __restrict__ ei, const float* __restrict__ hs,
    const float* __restrict__ hv, const float* __restrict__ pos,
    const float* __restrict__ ori, const float* __restrict__ W1,
    const float* __restrict__ b1, const float* __restrict__ W2,
    const float* __restrict__ b2, const int* __restrict__ flag64,
    float* __restrict__ out) {
    __shared__ float s_msg[IN_DIMC];
    __shared__ float s_h[HID];
    int e = blockIdx.x;
    int t = threadIdx.x;
    const bool i64 = (*flag64 != 0);
    int sN, dN;
    if (i64) {
        const long long* e64 = (const long long*)ei;
        sN = (int)e64[e]; dN = (int)e64[N_EDGESC + e];
    } else { sN = ei[e]; dN = ei[N_EDGESC + e]; }

    if (t < IN_DIMC) {
        if (t < 64) s_msg[t] = hs[sN * SDIM + t];
        else if (t < 128) s_msg[t] = hs[dN * SDIM + (t - 64)];
        else {
            float ca, sa, cb, sb;
            __sincosf(2.0f * ori[dN], &sa, &ca);
            __sincosf(2.0f * ori[sN], &sb, &cb);
            float c = cb * ca + sb * sa;
            float s = sb * ca - cb * sa;
            float dx = pos[2 * sN] - pos[2 * dN];
            float dy = pos[2 * sN + 1] - pos[2 * dN + 1];
            float d2 = dx * dx + dy * dy;
            if (t < 160) {
                int pr = (t - 128) >> 1;
                float x = hv[sN * VDIM + 2 * pr], y = hv[sN * VDIM + 2 * pr + 1];
                s_msg[t] = ((t & 1) == 0) ? (c * x - s * y) : (s * x + c * y);
            } else if (t == 160) s_msg[t] = sqrtf(d2) + 1e-6f;
            else {
                float c2f = 1.0f, s2f = 0.0f;
                if (d2 > 0.f) {
                    float inv = 1.0f / d2;
                    c2f = (dx * dx - dy * dy) * inv;
                    s2f = 2.0f * dx * dy * inv;
                }
                s_msg[t] = (t == 161) ? (c2f * ca + s2f * sa) : (s2f * ca - c2f * sa);
            }
        }
    }
    __syncthreads();
    if (t < HID) {
        float a = b1[t];
        for (int k = 0; k < IN_DIMC; ++k) a += s_msg[k] * W1[k * HID + t];
        s_h[t] = a / (1.0f + __expf(-a));
    }
    __syncthreads();
    if (t < HID) {
        float a = b2[t];
        for (int k = 0; k < HID; ++k) a += s_h[k] * W2[k * HID + t];
        if (t < SDIM) atomicAdd(&out[dN * SDIM + t], a);
        else atomicAdd(&out[N_NODESC * SDIM + dN * VDIM + (t - SDIM)], a);
    }
}

// ---------------------------------------------------------------------------
extern "C" void kernel_launch(void* const* d_in, const int* in_sizes, int n_in,
                              void* d_out, int out_size, void* d_ws, size_t ws_size,
                              hipStream_t stream) {
    const float* hs  = (const float*)d_in[0];
    const float* hv  = (const float*)d_in[1];
    const int*   ei  = (const int*)d_in[2];
    const float* pos = (const float*)d_in[3];
    const float* ori = (const float*)d_in[4];
    const float* W1  = (const float*)d_in[5];
    const float* b1  = (const float*)d_in[6];
    const float* W2  = (const float*)d_in[7];
    const float* b2  = (const float*)d_in[8];
    float* out = (float*)d_out;

    // sorted-tier workspace layout (256B-aligned chunks)
    const size_t SREC = (size_t)N_NODESC * 128 * sizeof(__hip_bfloat16);  // 12.8 MB
    const size_t QTB  = (size_t)N_NODESC * 96 * sizeof(__hip_bfloat16);   // 9.6 MB
    const size_t CNT  = ((size_t)N_NODESC * sizeof(int) + 255) & ~255ull; // 200 KB
    const size_t EDG  = (size_t)N_EDGESC * sizeof(int2);                  // 12.8 MB
    const size_t WBT2 = ((size_t)192 * 64 * 2 + 255) & ~255ull;
    const size_t W1CG = ((size_t)96 * 64 * 2 + 255) & ~255ull;
    const size_t W2TS = ((size_t)96 * 96 * 2 + 255) & ~255ull;
    const size_t FLG  = 256;
    const size_t DSC  = 1024;  // desc[196] padded
    const size_t SORT_WS = SREC + QTB + 2 * CNT + EDG + WBT2 + W1CG + W2TS
                         + FLG + DSC;

    const size_t TBL = (size_t)N_NODESC * HID * sizeof(__hip_bfloat16);   // 9.6 MB
    const bool big = ws_size >= 4 * TBL + 16;
    const bool srt = ws_size >= SORT_WS;

    if (srt) {
        char* ws = (char*)d_ws;
        __hip_bfloat16* SrcRec = (__hip_bfloat16*)(ws);
        __hip_bfloat16* Qt     = (__hip_bfloat16*)(ws + SREC);
        int* counts            = (int*)(ws + SREC + QTB);
        int* cur               = (int*)(ws + SREC + QTB + CNT);
        int2* edges            = (int2*)(ws + SREC + QTB + 2 * CNT);
        __hip_bfloat16* WbT2   = (__hip_bfloat16*)(ws + SREC + QTB + 2 * CNT + EDG);
        __hip_bfloat16* W1cgT  = (__hip_bfloat16*)(ws + SREC + QTB + 2 * CNT + EDG + WBT2);
        __hip_bfloat16* W2Tb   = (__hip_bfloat16*)(ws + SREC + QTB + 2 * CNT + EDG + WBT2 + W1CG);
        char* tail             = ws + SREC + QTB + 2 * CNT + EDG + WBT2 + W1CG + W2TS;
        int* flag              = (int*)(tail);
        int* desc              = (int*)(tail + FLG);

        // Host-side int64 detect from byte size (ambiguous -> in-kernel detect).
        int hostflag = -1;
        long long eib = (long long)in_sizes[2];
        if (eib == 2ll * N_EDGESC * 8) hostflag = 1;
        else if (eib == 2ll * N_EDGESC * 4) hostflag = 0;

        prep_kernel<<<SCB, 256, 0, stream>>>(ei, hostflag, flag, W1, W2,
                                             WbT2, W1cgT, W2Tb, counts, desc);
        init_hist_precompute<<<NPRE + N_EDGESC / 256, 256, 0, stream>>>(
            hs, hv, out, counts, ei, flag, WbT2, b1, SrcRec, Qt);
        scan_onepass<<<SCB, 256, 0, stream>>>(counts, cur, desc);
        scatter_kernel<<<N_EDGESC / 256, 256, 0, stream>>>(ei, flag, cur, edges);
        edge_kernel_sorted<<<GRID_E, 256, 0, stream>>>(edges, pos, ori, W2Tb, b2,
                                                       SrcRec, Qt, W1cgT, out);
    } else if (big) {
        char* ws = (char*)d_ws;
        __hip_bfloat16* Pp = (__hip_bfloat16*)(ws);
        __hip_bfloat16* Qt = (__hip_bfloat16*)(ws + TBL);
        __hip_bfloat16* Ut = (__hip_bfloat16*)(ws + 2 * TBL);
        __hip_bfloat16* Vt = (__hip_bfloat16*)(ws + 3 * TBL);
        int* flag = (int*)(ws + 4 * TBL);
        init_out<<<(N_NODESC * (SDIM + VDIM) + 255) / 256, 256, 0, stream>>>(hs, hv, out);
        detect_kernel<<<1, 64, 0, stream>>>(ei, flag);
        node_precompute<<<N_NODESC, 128, 0, stream>>>(hs, hv, W1, b1, Pp, Qt, Ut, Vt);
        edge_kernel<<<2500, 256, 0, stream>>>(ei, pos, ori, W1, W2, b2,
                                              Pp, Qt, Ut, Vt, flag, out);
    } else {
        int* flag = (int*)d_ws;
        init_out<<<(N_NODESC * (SDIM + VDIM) + 255) / 256, 256, 0, stream>>>(hs, hv, out);
        detect_kernel<<<1, 64, 0, stream>>>(ei, flag);
        edge_fallback<<<N_EDGESC, 192, 0, stream>>>(ei, hs, hv, pos, ori, W1, b1,
                                                    W2, b2, flag, out);
    }
}